// Round 1
// baseline (2368.179 us; speedup 1.0000x reference)
//
#include <hip/hip_runtime.h>
#include <hip/hip_bf16.h>
#include <stdint.h>

typedef __bf16 bf16x8 __attribute__((ext_vector_type(8)));
typedef float  floatx4 __attribute__((ext_vector_type(4)));

static constexpr int kT = 512, kH = 1024, k4H = 4096;

// ---------------------------------------------------------------------------
// Weight pack: wpk[np(256)][c(64)][lane(64)][j(8)] bf16  (MFMA B-fragment order)
//   n_local = lane&15 = hl*4 + g  (gates interleaved inside each 16-wide n-tile)
//   col_W   = g*1024 + np*4 + hl ;  np = cg*4 + nt  ->  hcol = cg*16 + nt*4 + hl
//   fused k = c*32 + (lane>>4)*8 + j   (c<32: Wx rows, c>=32: Wh rows)
// ---------------------------------------------------------------------------
__global__ void pack_w(const float* __restrict__ Wx, const float* __restrict__ Wh,
                       __bf16* __restrict__ wpk) {
  int idx = blockIdx.x * 256 + threadIdx.x;          // 1,048,576 threads
  int l  = idx & 63;
  int c  = (idx >> 6) & 63;
  int np = idx >> 12;                                // 0..255
  int nl = l & 15;
  int g  = nl & 3, hl = nl >> 2;
  int col = g * kH + np * 4 + hl;
  int kf  = (l >> 4) * 8;
  const float* src = (c < 32) ? Wx + (size_t)(c * 32 + kf) * k4H + col
                              : Wh + (size_t)((c - 32) * 32 + kf) * k4H + col;
  bf16x8 v;
#pragma unroll
  for (int j = 0; j < 8; ++j) v[j] = (__bf16)src[(size_t)j * k4H];
  *(bf16x8*)(wpk + (size_t)idx * 8) = v;
}

// ---------------------------------------------------------------------------
// x pack: xpk[t][mt(4)][c(32)][lane(64)][j(8)] bf16  (MFMA A-fragment order)
//   m = mt*16 + (lane&15),  k = c*32 + (lane>>4)*8 + j
// ---------------------------------------------------------------------------
__global__ void pack_x(const float* __restrict__ x, __bf16* __restrict__ xpk) {
  int idx = blockIdx.x * 256 + threadIdx.x;          // 4,194,304 threads
  int l  = idx & 63;
  int c  = (idx >> 6) & 31;
  int mt = (idx >> 11) & 3;
  int t  = idx >> 13;
  int m  = mt * 16 + (l & 15);
  int f  = c * 32 + (l >> 4) * 8;
  const float4* src = (const float4*)(x + ((size_t)m * kT + t) * 1024 + f);
  float4 r0 = src[0], r1 = src[1];
  bf16x8 v;
  v[0] = (__bf16)r0.x; v[1] = (__bf16)r0.y; v[2] = (__bf16)r0.z; v[3] = (__bf16)r0.w;
  v[4] = (__bf16)r1.x; v[5] = (__bf16)r1.y; v[6] = (__bf16)r1.z; v[7] = (__bf16)r1.w;
  *(bf16x8*)(xpk + (size_t)idx * 8) = v;
}

// ---------------------------------------------------------------------------
// Persistent scan, 256 WGs x 512 thr (1 WG/CU). WG = (cg 0..63, mq 0..3).
//
// h exchange, SELF-TAGGED DATA (no sentinels, no producer-side vmcnt drain):
//   Each even-ghc gate thread stores ONE 8-byte atomic qword per step:
//       { lo dword = 2 x bf16 h values, hi dword = tag = t }.
//   Consumers speculatively issue all 32 qword loads for their slice, verify
//   every tag == t, and retry ONLY mismatched words (s_sleep throttled).
//   The poll IS the data load -> the chain is ~2 fabric round trips instead
//   of 4 (old: B3 vmcnt(0) drain -> sentinel store -> sentinel poll -> load).
//
// Ring: 4 slots. Overwrite margin (no sentinels needed): publishing t+4
// requires having consumed verified-tag t+3 data from ALL producers, which
// transitively requires every WG completed its slot-(t&3) reads (3-step
// margin). Per-word tag verification turns any stale read into a retry.
// Init/poison/cross-launch safety: ring memset to 0xFF before each scan
// launch (tag 0xFFFFFFFF never matches t < 512).
//
// Barriers are raw s_barrier: B2 needs only lgkmcnt(0) (zbuf LDS ordering);
// B3 needs no waitcnt at all (zbuf read values already consumed). Gate waves
// therefore pass B3 right after ISSUING h/out stores - no drain on the
// critical path.
//
// hq layout (qwords): [slot(4)][mq(4)][kpair(512)][row(16)]
//   kpair = hcol>>1, row = m&15
// ---------------------------------------------------------------------------
__launch_bounds__(512, 2)
__global__ void lstm_scan(const __bf16* __restrict__ xpk, const __bf16* __restrict__ wpk,
                          const float* __restrict__ bias, uint64_t* __restrict__ hq,
                          float* __restrict__ out) {
  const int blk  = blockIdx.x;
  const int half = blk & 1;
  const int mq   = (blk >> 1) & 3;
  const int cg   = half * 32 + (blk >> 3);           // 0..63
  const int tid  = threadIdx.x;
  const int wave = tid >> 6;                         // 0..7
  const int lane = tid & 63;

  __shared__ __align__(16) float zbuf[8][16][68];

  // ---- persistent weight fragments: breg[ntile][chunk], chunk = wave*8+cc ----
  bf16x8 breg[4][8];
#pragma unroll
  for (int nt = 0; nt < 4; ++nt) {
    const __bf16* wsrc = wpk + (((size_t)(cg * 4 + nt) * 64 + wave * 8) * 64 + lane) * 8;
#pragma unroll
    for (int cc = 0; cc < 8; ++cc)
      breg[nt][cc] = *(const bf16x8*)(wsrc + (size_t)cc * 512);
  }
#pragma unroll
  for (int nt = 0; nt < 4; ++nt)
#pragma unroll
    for (int cc = 0; cc < 8; ++cc)
      asm volatile("" : "+v"(breg[nt][cc]));         // pin: no remat from memory

  // ---- gate-phase per-thread state (threads 0..255) ----
  const int gm   = (tid >> 4) & 15;
  const int ghc  = tid & 15;
  const int m_g  = mq * 16 + gm;
  const int hcol = cg * 16 + ghc;
  const int gnt  = ghc >> 2, ghl = ghc & 3;
  float c_state  = 0.f;
  const float bi = bias[0 * kH + hcol], bf_ = bias[1 * kH + hcol];
  const float bg = bias[2 * kH + hcol], bo  = bias[3 * kH + hcol];
  // qword index within a slot for this producer thread's h pair
  const int qoff = ((mq * 512 + cg * 8 + (ghc >> 1)) * 16) + gm;

  floatx4 acc[4];
#pragma unroll
  for (int nt = 0; nt < 4; ++nt) acc[nt] = floatx4{0.f, 0.f, 0.f, 0.f};

  // ---- prologue: x-part of t=0 (h_{-1}=0 so h-waves contribute zero) ----
  if (wave < 4) {
    const __bf16* asrc = xpk + ((size_t)mq * 32 + wave * 8) * 512 + (size_t)lane * 8;
#pragma unroll
    for (int cc = 0; cc < 8; ++cc) {
      bf16x8 a = *(const bf16x8*)(asrc + (size_t)cc * 512);
#pragma unroll
      for (int nt = 0; nt < 4; ++nt)
        acc[nt] = __builtin_amdgcn_mfma_f32_16x16x32_bf16(a, breg[nt][cc], acc[nt], 0, 0, 0);
    }
  }

#pragma unroll 1
  for (int t = 0; t < kT; ++t) {
    // publish partials to LDS (all zbuf readers of step t-1 passed B3 already)
#pragma unroll
    for (int nt = 0; nt < 4; ++nt)
#pragma unroll
      for (int rr = 0; rr < 4; ++rr)
        zbuf[wave][(lane >> 4) * 4 + rr][nt * 16 + (lane & 15)] = acc[nt][rr];
    // B2: zbuf writes visible to all waves (LDS ordering only)
    asm volatile("s_waitcnt lgkmcnt(0)" ::: "memory");
    __builtin_amdgcn_s_barrier();
    asm volatile("" ::: "memory");

    if (tid < 256) {
      float zi = bi, zf = bf_, zg = bg, zo = bo;
      const float* zp = &zbuf[0][gm][gnt * 16 + ghl * 4];
#pragma unroll
      for (int w = 0; w < 8; ++w) {
        floatx4 zv = *(const floatx4*)(zp + (size_t)w * 16 * 68);
        zi += zv[0]; zf += zv[1]; zg += zv[2]; zo += zv[3];
      }
      float ig = 1.f / (1.f + __expf(-zi));
      float fg = 1.f / (1.f + __expf(-zf));
      float gg = 2.f / (1.f + __expf(-2.f * zg)) - 1.f;
      float og = 1.f / (1.f + __expf(-zo));
      c_state = fg * c_state + ig * gg;
      float tc = 2.f / (1.f + __expf(-2.f * c_state)) - 1.f;
      float h  = og * tc;
      // publish tagged h qword FIRST (critical path), then the nt out-store
      __bf16 hb16 = (__bf16)h;
      uint16_t hbits;
      __builtin_memcpy(&hbits, &hb16, 2);
      uint32_t mine = hbits;
      uint32_t partner = (uint32_t)__shfl_xor((int)mine, 1);   // ghc^1, same wave
      if ((ghc & 1) == 0) {
        uint64_t qw = ((uint64_t)(uint32_t)t << 32)
                    | (uint64_t)(mine | (partner << 16));
        __hip_atomic_store(&hq[(size_t)(t & 3) * 32768 + qoff], qw,
                           __ATOMIC_RELAXED, __HIP_MEMORY_SCOPE_AGENT);
      }
      __builtin_nontemporal_store(h, &out[((size_t)m_g * kT + t) * kH + hcol]);
    }
    // B3: protect zbuf reuse only — NO vmcnt drain (stores retire in background)
    asm volatile("" ::: "memory");
    __builtin_amdgcn_s_barrier();
    asm volatile("" ::: "memory");

    // ---- tail: partials for step t+1 ----
    if (t < kT - 1) {
#pragma unroll
      for (int nt = 0; nt < 4; ++nt) acc[nt] = floatx4{0.f, 0.f, 0.f, 0.f};
      if (wave < 4) {                                // x-part of t+1: runs ahead
        const __bf16* asrc = xpk + (((size_t)(t + 1) * 4 + mq) * 32 + wave * 8) * 512
                           + (size_t)lane * 8;
#pragma unroll
        for (int cc = 0; cc < 8; ++cc) {
          bf16x8 a = __builtin_nontemporal_load((const bf16x8*)(asrc + (size_t)cc * 512));
#pragma unroll
          for (int nt = 0; nt < 4; ++nt)
            acc[nt] = __builtin_amdgcn_mfma_f32_16x16x32_bf16(a, breg[nt][cc], acc[nt], 0, 0, 0);
        }
      } else {                                       // h-part: tagged speculative load
        const int s = wave - 4;
        // qword base: [slot][mq][kpair = s*128 + c*16 + (lane>>4)*4 + d][lane&15]
        const uint64_t* hb = hq + (size_t)(t & 3) * 32768 + (size_t)mq * 8192
                           + (size_t)s * 2048 + (lane >> 4) * 64 + (lane & 15);
        const uint32_t tagv = (uint32_t)t;
        uint64_t w[8][4];
#pragma unroll
        for (int c = 0; c < 8; ++c)
#pragma unroll
          for (int d = 0; d < 4; ++d)
            w[c][d] = __hip_atomic_load(hb + (size_t)c * 256 + d * 16,
                                        __ATOMIC_RELAXED, __HIP_MEMORY_SCOPE_AGENT);
        int guard = 0;
        for (;;) {
          bool ok = true;
#pragma unroll
          for (int c = 0; c < 8; ++c)
#pragma unroll
            for (int d = 0; d < 4; ++d)
              ok = ok && ((uint32_t)(w[c][d] >> 32) == tagv);
          if (__all(ok)) break;                      // every lane's 32 tags match
          __builtin_amdgcn_s_sleep(2);
#pragma unroll
          for (int c = 0; c < 8; ++c)
#pragma unroll
            for (int d = 0; d < 4; ++d)
              if ((uint32_t)(w[c][d] >> 32) != tagv)
                w[c][d] = __hip_atomic_load(hb + (size_t)c * 256 + d * 16,
                                            __ATOMIC_RELAXED, __HIP_MEMORY_SCOPE_AGENT);
          if (++guard > (1 << 20)) break;            // fail loud, not hung
        }
        asm volatile("" ::: "memory");               // no hoisting past the verify
#pragma unroll
        for (int c = 0; c < 8; ++c) {
          union { uint32_t d[4]; bf16x8 v; } u;
#pragma unroll
          for (int d0 = 0; d0 < 4; ++d0) u.d[d0] = (uint32_t)w[c][d0];
#pragma unroll
          for (int nt = 0; nt < 4; ++nt)
            acc[nt] = __builtin_amdgcn_mfma_f32_16x16x32_bf16(u.v, breg[nt][c], acc[nt], 0, 0, 0);
        }
      }
    }
  }
}

// ---------------------------------------------------------------------------
extern "C" void kernel_launch(void* const* d_in, const int* in_sizes, int n_in,
                              void* d_out, int out_size, void* d_ws, size_t ws_size,
                              hipStream_t stream) {
  const float* x  = (const float*)d_in[0];   // [64,512,1024]
  const float* Wx = (const float*)d_in[1];   // [1024,4096]
  const float* Wh = (const float*)d_in[2];   // [1024,4096]
  const float* b  = (const float*)d_in[3];   // [4096]
  float* out = (float*)d_out;

  char* ws = (char*)d_ws;
  uint64_t* hdq = (uint64_t*)ws;                            // 1 MB tagged-h ring
  __bf16*   wpk = (__bf16*)(ws + ((size_t)1 << 20));        // 16 MB
  __bf16*   xpk = (__bf16*)(ws + ((size_t)17 << 20));       // 64 MB  (total 81 MB)
  (void)in_sizes; (void)n_in; (void)out_size; (void)ws_size;

  // tag-poison the ring: 0xFFFFFFFF never equals a valid tag t < 512
  hipMemsetAsync(hdq, 0xFF, (size_t)1 << 20, stream);

  hipLaunchKernelGGL(pack_w, dim3(4096),  dim3(256), 0, stream, Wx, Wh, wpk);
  hipLaunchKernelGGL(pack_x, dim3(16384), dim3(256), 0, stream, x, xpk);
  hipLaunchKernelGGL(lstm_scan, dim3(256), dim3(512), 0, stream,
                     xpk, wpk, b, hdq, out);
}